// Round 11
// baseline (165.664 us; speedup 1.0000x reference)
//
#include <hip/hip_runtime.h>
#include <hip/hip_bf16.h>

#define HCn 4
#define Cn 2048
#define Dn (HCn*Cn)       // 8192
#define NLg 24            // HC*HC + 2*HC
#define TMAXn 8
#define TSx 8240          // LDS token stride (bf16 elems) = 16480 B; banks spread 0/24/16/8

typedef short bf16x8 __attribute__((ext_vector_type(8)));
typedef float f32x4 __attribute__((ext_vector_type(4)));

__device__ __forceinline__ unsigned int pk2(float a, float b) {
  union { __hip_bfloat162 h; unsigned int u; } v;
  v.h = __float22bfloat162_rn(float2{a, b});
  return v.u;
}
__device__ __forceinline__ unsigned short f2bfu(float a) {
  union { __hip_bfloat16 h; unsigned short u; } v;
  v.h = __float2bfloat16(a);
  return v.u;
}
__device__ __forceinline__ float bf2f(unsigned int u16) {
  union { float f; unsigned int x; } v;
  v.x = u16 << 16;
  return v.f;
}
__device__ __forceinline__ float sigm(float z) { return 1.0f / (1.0f + expf(-z)); }

__device__ __forceinline__ void gload_lds16(const void* g, void* l) {
  __builtin_amdgcn_global_load_lds((__attribute__((address_space(1))) void*)(g),
                                   (__attribute__((address_space(3))) void*)(l),
                                   16, 0, 0);
}

// ---------------- Kernel 0: phi [8192][24] -> phiB B-fragment layout (bf16) ----------
__global__ __launch_bounds__(128) void phib_kernel(const float* __restrict__ phi,
                                                   unsigned short* __restrict__ phiB) {
  int tid = threadIdx.x;
  int nt = tid >> 6, lane = tid & 63;
  int ks = blockIdx.x;
  int col = nt * 16 + (lane & 15);
  int kb = ks * 32 + (lane >> 4) * 8;
  float v[8];
#pragma unroll
  for (int e = 0; e < 8; ++e)
    v[e] = (col < NLg) ? phi[(size_t)(kb + e) * NLg + col] : 0.f;
  uint4 o = { pk2(v[0], v[1]), pk2(v[2], v[3]), pk2(v[4], v[5]), pk2(v[6], v[7]) };
  *(uint4*)&phiB[((size_t)(ks * 2 + nt) * 64 + lane) * 8] = o;
}

// ------- Kernel 1: FUSED coeffs — logits (MFMA, full K) + Sinkhorn + x_in, 4 tok/block
// x staged once into LDS (bf16); xin computed from LDS (no second HBM read of x).
__global__ __launch_bounds__(512) void coeffs_kernel(
    const float* __restrict__ x, const unsigned short* __restrict__ phiB,
    const float* __restrict__ bb, const float* __restrict__ apre_p,
    const float* __restrict__ apost_p, const float* __restrict__ ares_p,
    unsigned int* __restrict__ xin, float* __restrict__ hpost,
    float* __restrict__ hres) {
  __shared__ __align__(16) unsigned short xls[4 * TSx];   // 65,920 B
  __shared__ float lgp[8][4][33];
  __shared__ float ssw[8][4];
  __shared__ float hpre_s[4][4];

  int tid = threadIdx.x, lane = tid & 63, wid = tid >> 6;
  long t0 = (long)blockIdx.x * 4;
  const float4* xb = (const float4*)(x + (size_t)t0 * Dn);

  // ---- Phase S: stage x -> LDS bf16, accumulate per-token sum-of-squares (f32) ----
  float ss[4] = {0.f, 0.f, 0.f, 0.f};
#pragma unroll
  for (int p = 0; p < 8; ++p) {
    int idx = p * 4096 + tid * 8;      // element in [0, 32768)
    int tok = p >> 1;                  // 8192 elems per token
    int ch = idx & 8191;
    float4 v0 = xb[idx >> 2];
    float4 v1 = xb[(idx >> 2) + 1];
    ss[tok] += v0.x*v0.x + v0.y*v0.y + v0.z*v0.z + v0.w*v0.w
             + v1.x*v1.x + v1.y*v1.y + v1.z*v1.z + v1.w*v1.w;
    uint4 u = { pk2(v0.x,v0.y), pk2(v0.z,v0.w), pk2(v1.x,v1.y), pk2(v1.z,v1.w) };
    *(uint4*)&xls[tok * TSx + ch] = u;
  }
#pragma unroll
  for (int j = 0; j < 4; ++j) {
    float s = ss[j];
    s += __shfl_xor(s, 1);  s += __shfl_xor(s, 2);  s += __shfl_xor(s, 4);
    s += __shfl_xor(s, 8);  s += __shfl_xor(s, 16); s += __shfl_xor(s, 32);
    if (lane == 0) ssw[wid][j] = s;
  }
  __syncthreads();

  // ---- Phase L: logits via MFMA. A rows duplicate token (l15&3); wave K-window 1024.
  {
    int l15 = lane & 15, sg = lane >> 4;
    const unsigned short* arow = &xls[(l15 & 3) * TSx];
    int kwin = wid * 1024;
    const bf16x8* pB = (const bf16x8*)phiB + (size_t)(kwin >> 5) * 128 + lane;
    f32x4 acc0 = {0.f,0.f,0.f,0.f}, acc1 = {0.f,0.f,0.f,0.f};
#pragma unroll
    for (int it = 0; it < 32; ++it) {
      int k = kwin + it * 32 + sg * 8;
      bf16x8 a = *(const bf16x8*)&arow[k];
      bf16x8 b0 = pB[it * 128];
      bf16x8 b1 = pB[it * 128 + 64];
      acc0 = __builtin_amdgcn_mfma_f32_16x16x32_bf16(a, b0, acc0, 0, 0, 0);
      acc1 = __builtin_amdgcn_mfma_f32_16x16x32_bf16(a, b1, acc1, 0, 0, 0);
    }
    // C: col=lane&15, row=sg*4+e -> token = (sg*4+e)&3 = e. Every lane holds all 4 tokens.
    if (sg == 0) {
#pragma unroll
      for (int e = 0; e < 4; ++e) {
        lgp[wid][e][l15] = acc0[e];
        lgp[wid][e][16 + l15] = acc1[e];
      }
    }
  }
  __syncthreads();

  // ---- Phase F: finalize (4 tokens, 4 threads) ----
  if (tid < 4) {
    long t = t0 + tid;
    float st = 0.f;
#pragma unroll
    for (int w = 0; w < 8; ++w) st += ssw[w][tid];
    float r = rsqrtf(st / (float)Dn + 1e-6f);
    float apre = apre_p[0], apost = apost_p[0], ares = ares_p[0];
    float lg[NLg];
#pragma unroll
    for (int j = 0; j < NLg; ++j) {
      float d = 0.f;
#pragma unroll
      for (int w = 0; w < 8; ++w) d += lgp[w][tid][j];
      lg[j] = r * d + bb[j];
    }
#pragma unroll
    for (int j = 0; j < 4; ++j) hpre_s[tid][j] = sigm(apre * lg[j]) + 1e-4f;
#pragma unroll
    for (int j = 0; j < 4; ++j) hpost[t * 4 + j] = 2.0f * sigm(apost * lg[4 + j]);
    float m[16];
#pragma unroll
    for (int q = 0; q < 16; ++q) m[q] = expf(ares * lg[8 + q]);
    for (int it = 0; it < TMAXn; ++it) {
#pragma unroll
      for (int o = 0; o < 4; ++o) {
        float rs = m[o*4] + m[o*4+1] + m[o*4+2] + m[o*4+3] + 1e-6f;
        m[o*4] /= rs; m[o*4+1] /= rs; m[o*4+2] /= rs; m[o*4+3] /= rs;
      }
#pragma unroll
      for (int i = 0; i < 4; ++i) {
        float cs = m[i] + m[4+i] + m[8+i] + m[12+i] + 1e-6f;
        m[i] /= cs; m[4+i] /= cs; m[8+i] /= cs; m[12+i] /= cs;
      }
    }
#pragma unroll
    for (int q = 0; q < 16; ++q) hres[t * 16 + q] = m[q];
  }
  __syncthreads();

  // ---- Phase X: x_in from LDS (bf16), 128 threads per token, 16 ch each ----
  {
    int tk = tid >> 7;
    int c0 = (tid & 127) * 16;
    float h0 = hpre_s[tk][0], h1 = hpre_s[tk][1], h2 = hpre_s[tk][2], h3 = hpre_s[tk][3];
    float s[16];
#pragma unroll
    for (int i = 0; i < 16; ++i) s[i] = 0.f;
#pragma unroll
    for (int hc = 0; hc < 4; ++hc) {
      float h = (hc == 0) ? h0 : (hc == 1) ? h1 : (hc == 2) ? h2 : h3;
      int base = tk * TSx + hc * 2048 + c0;
      uint4 u0 = *(const uint4*)&xls[base];
      uint4 u1 = *(const uint4*)&xls[base + 8];
      s[0]  += h * bf2f(u0.x & 0xffffu); s[1]  += h * bf2f(u0.x >> 16);
      s[2]  += h * bf2f(u0.y & 0xffffu); s[3]  += h * bf2f(u0.y >> 16);
      s[4]  += h * bf2f(u0.z & 0xffffu); s[5]  += h * bf2f(u0.z >> 16);
      s[6]  += h * bf2f(u0.w & 0xffffu); s[7]  += h * bf2f(u0.w >> 16);
      s[8]  += h * bf2f(u1.x & 0xffffu); s[9]  += h * bf2f(u1.x >> 16);
      s[10] += h * bf2f(u1.y & 0xffffu); s[11] += h * bf2f(u1.y >> 16);
      s[12] += h * bf2f(u1.z & 0xffffu); s[13] += h * bf2f(u1.z >> 16);
      s[14] += h * bf2f(u1.w & 0xffffu); s[15] += h * bf2f(u1.w >> 16);
    }
    unsigned short* xo = (unsigned short*)xin + ((size_t)(t0 + tk) * Cn + c0);
    uint4 o0 = { pk2(s[0], s[1]),  pk2(s[2], s[3]),  pk2(s[4], s[5]),  pk2(s[6], s[7]) };
    uint4 o1 = { pk2(s[8], s[9]),  pk2(s[10],s[11]), pk2(s[12],s[13]), pk2(s[14],s[15]) };
    *(uint4*)&xo[0] = o0;
    *(uint4*)&xo[8] = o1;
  }
}

// ---------------- Kernel 2: W (K x N, f32) -> Wt (N x K, bf16) ----------------
__global__ __launch_bounds__(256) void wtrans_kernel(const float* __restrict__ W,
                                                     unsigned short* __restrict__ Wt) {
  __shared__ float tile[64][65];
  int kb = blockIdx.y * 64, nb = blockIdx.x * 64;
  int tr = threadIdx.x >> 4;
  int tc = threadIdx.x & 15;
#pragma unroll
  for (int rr = 0; rr < 64; rr += 16) {
    float4 v = *(const float4*)&W[(size_t)(kb + tr + rr) * Cn + nb + tc * 4];
    tile[tr + rr][tc * 4 + 0] = v.x; tile[tr + rr][tc * 4 + 1] = v.y;
    tile[tr + rr][tc * 4 + 2] = v.z; tile[tr + rr][tc * 4 + 3] = v.w;
  }
  __syncthreads();
#pragma unroll
  for (int rr = 0; rr < 64; rr += 16) {
    int n = nb + tr + rr;
    uint2 o;
    o.x = pk2(tile[tc * 4 + 0][tr + rr], tile[tc * 4 + 1][tr + rr]);
    o.y = pk2(tile[tc * 4 + 2][tr + rr], tile[tc * 4 + 3][tr + rr]);
    *(uint2*)&Wt[(size_t)n * Cn + kb + tc * 4] = o;
  }
}

// ---- Kernel 3: bf16 MFMA GEMM, BK=64 dbuf + XOR-swizzled LDS + counted-vmcnt pipeline
#define BMt 128
#define BNt 128
#define BKt 64
#define GK Cn
__global__ __launch_bounds__(256) void gemm_kernel(
    const unsigned short* __restrict__ xin, const unsigned short* __restrict__ Wt,
    const float* __restrict__ Wb, unsigned short* __restrict__ f) {
  __shared__ __align__(16) unsigned short As[2][BMt * BKt];
  __shared__ __align__(16) unsigned short Bs[2][BNt * BKt];
  int tid = threadIdx.x;
  int lane = tid & 63, wid = tid >> 6;
  int wr = wid >> 1, wc = wid & 1;
  int l15 = lane & 15, kg = lane >> 4;
  int wg = blockIdx.x;
  wg = (wg & 7) * 64 + (wg >> 3);   // XCD swizzle (512 % 8 == 0, bijective)
  int bx = wg & 15, by = wg >> 4;

  f32x4 acc[4][4];
#pragma unroll
  for (int i = 0; i < 4; ++i)
#pragma unroll
    for (int j = 0; j < 4; ++j) acc[i][j] = {0.f, 0.f, 0.f, 0.f};

  const char* Ab = (const char*)xin + (size_t)by * BMt * (GK * 2);
  const char* Bb = (const char*)Wt + (size_t)bx * BNt * (GK * 2);

  int soff[4]; size_t sgl[4];
#pragma unroll
  for (int i = 0; i < 4; ++i) {
    int off = tid * 16 + i * 4096;
    int row = off >> 7, col = off & 127;
    int scol = col ^ ((row & 7) << 4);
    soff[i] = off;
    sgl[i] = (size_t)row * (GK * 2) + scol;
  }
#define STAGEG(BUF, K0) {                                                      \
    _Pragma("unroll")                                                          \
    for (int i_ = 0; i_ < 4; ++i_)                                             \
      gload_lds16(Ab + sgl[i_] + (size_t)(K0) * 2, (char*)As[BUF] + soff[i_]); \
    _Pragma("unroll")                                                          \
    for (int i_ = 0; i_ < 4; ++i_)                                             \
      gload_lds16(Bb + sgl[i_] + (size_t)(K0) * 2, (char*)Bs[BUF] + soff[i_]); }

  int aoff[4][2], boff[4][2];
#pragma unroll
  for (int fm = 0; fm < 4; ++fm) {
    int ar = wr * 64 + fm * 16 + l15;
    int br = wc * 64 + fm * 16 + l15;
#pragma unroll
    for (int ks = 0; ks < 2; ++ks) {
      int c = ks * 64 + kg * 16;
      aoff[fm][ks] = ar * 128 + (c ^ ((ar & 7) << 4));
      boff[fm][ks] = br * 128 + (c ^ ((br & 7) << 4));
    }
  }

  STAGEG(0, 0);
  asm volatile("s_waitcnt vmcnt(0)" ::: "memory");
  __builtin_amdgcn_s_barrier();

  for (int t = 0; t < GK / BKt; ++t) {
    int cur = t & 1;
    if (t < GK / BKt - 1) STAGEG(cur ^ 1, (t + 1) * BKt);
#pragma unroll
    for (int ks = 0; ks < 2; ++ks) {
      bf16x8 av[4], bv[4];
#pragma unroll
      for (int fm = 0; fm < 4; ++fm)
        av[fm] = *(const bf16x8*)((const char*)As[cur] + aoff[fm][ks]);
#pragma unroll
      for (int fn = 0; fn < 4; ++fn)
        bv[fn] = *(const bf16x8*)((const char*)Bs[cur] + boff[fn][ks]);
#pragma unroll
      for (int fm = 0; fm < 4; ++fm)
#pragma unroll
        for (int fn = 0; fn < 4; ++fn)
          acc[fm][fn] = __builtin_amdgcn_mfma_f32_16x16x32_bf16(av[fm], bv[fn], acc[fm][fn], 0, 0, 0);
    }
    asm volatile("s_waitcnt vmcnt(0)" ::: "memory");
    __builtin_amdgcn_s_barrier();
  }

  int m0 = by * BMt + wr * 64;
  int n0 = bx * BNt + wc * 64;
#pragma unroll
  for (int fm = 0; fm < 4; ++fm) {
#pragma unroll
    for (int e = 0; e < 4; ++e) {
      int t = m0 + fm * 16 + kg * 4 + e;
      unsigned short* ft = f + (size_t)t * Cn;
#pragma unroll
      for (int fn = 0; fn < 4; ++fn) {
        int c = n0 + fn * 16 + l15;
        ft[c] = f2bfu(acc[fm][fn][e] + Wb[c]);
      }
    }
  }
}

// ---------------- Kernel 4: streaming epilogue (one token per block, NT stores) ------
__global__ __launch_bounds__(256) void epilogue_kernel(
    const float* __restrict__ x, const unsigned short* __restrict__ f,
    const float* __restrict__ hpost, const float* __restrict__ hres,
    float* __restrict__ out) {
  long t = blockIdx.x;
  int tid = threadIdx.x;
  float hq[4], hr[16];
#pragma unroll
  for (int o = 0; o < 4; ++o) hq[o] = hpost[t * 4 + o];
#pragma unroll
  for (int q = 0; q < 16; ++q) hr[q] = hres[t * 16 + q];
  const float4* xt = (const float4*)(x + (size_t)t * Dn);
  const uint2* ft = (const uint2*)(f + (size_t)t * Cn);
  float* ot = out + (size_t)t * Dn;
#pragma unroll
  for (int it = 0; it < 2; ++it) {
    int c4 = it * 256 + tid;
    float4 x0 = xt[c4], x1 = xt[c4 + 512], x2 = xt[c4 + 1024], x3 = xt[c4 + 1536];
    uint2 fu = ft[c4];
    float4 fv = { bf2f(fu.x & 0xffffu), bf2f(fu.x >> 16),
                  bf2f(fu.y & 0xffffu), bf2f(fu.y >> 16) };
#pragma unroll
    for (int o = 0; o < 4; ++o) {
      float a = hr[o*4+0], b = hr[o*4+1], c = hr[o*4+2], d = hr[o*4+3], q = hq[o];
      f32x4 r;
      r[0] = q*fv.x + a*x0.x + b*x1.x + c*x2.x + d*x3.x;
      r[1] = q*fv.y + a*x0.y + b*x1.y + c*x2.y + d*x3.y;
      r[2] = q*fv.z + a*x0.z + b*x1.z + c*x2.z + d*x3.z;
      r[3] = q*fv.w + a*x0.w + b*x1.w + c*x2.w + d*x3.w;
      __builtin_nontemporal_store(r, (f32x4*)&ot[(size_t)o * Cn + c4 * 4]);
    }
  }
}

extern "C" void kernel_launch(void* const* d_in, const int* in_sizes, int n_in,
                              void* d_out, int out_size, void* d_ws, size_t ws_size,
                              hipStream_t stream) {
  const float* x     = (const float*)d_in[0];
  const float* phi   = (const float*)d_in[1];
  const float* b     = (const float*)d_in[2];
  const float* apre  = (const float*)d_in[3];
  const float* apost = (const float*)d_in[4];
  const float* ares  = (const float*)d_in[5];
  const float* W     = (const float*)d_in[6];
  const float* Wb    = (const float*)d_in[7];
  float* out = (float*)d_out;

  int NT = in_sizes[0] / Dn;   // 4096 tokens
  char* ws = (char*)d_ws;
  size_t off = 0;
  unsigned int*   xin  = (unsigned int*)(ws + off);   off += (size_t)NT * Cn * 2;   // 16 MB
  unsigned short* Wt   = (unsigned short*)(ws + off); off += (size_t)Cn * Cn * 2;   // 8 MB
  float* hpost = (float*)(ws + off); off += (size_t)NT * 4 * 4;
  float* hres  = (float*)(ws + off); off += (size_t)NT * 16 * 4;
  unsigned short* phiB = (unsigned short*)(ws + off); off += (size_t)Dn * 32 * 2;   // 512 KB
  unsigned short* fbuf = (unsigned short*)(ws + off); off += (size_t)NT * Cn * 2;   // 16 MB

  hipLaunchKernelGGL(phib_kernel, dim3(Dn / 32), dim3(128), 0, stream, phi, phiB);
  hipLaunchKernelGGL(coeffs_kernel, dim3(NT / 4), dim3(512), 0, stream,
                     x, phiB, b, apre, apost, ares, xin, hpost, hres);
  hipLaunchKernelGGL(wtrans_kernel, dim3(Cn / 64, Cn / 64), dim3(256), 0, stream, W, Wt);
  hipLaunchKernelGGL(gemm_kernel, dim3((Cn / BNt) * (NT / BMt)), dim3(256), 0, stream,
                     (const unsigned short*)xin, Wt, Wb, fbuf);
  hipLaunchKernelGGL(epilogue_kernel, dim3(NT), dim3(256), 0, stream,
                     x, fbuf, hpost, hres, out);
}